// Round 1
// baseline (626.868 us; speedup 1.0000x reference)
//
#include <hip/hip_runtime.h>
#include <math.h>

// Problem constants (from reference)
#define NSEQ   2048
#define HEADS  8
#define HD     16     // head_dim == v_head_dim
#define NROWS  8192   // B*N
// BH = 32

// ---------------------------------------------------------------------------
// Kernel 1: fused Q/K/V projection.
// q = (query @ Wq^T + bq) * 0.25 ; k = key @ Wk^T + bk ; v = value @ Wv^T + bv
// Output layout: [B*H][N][16] (head-major) for attention locality.
// grid 512, block 256; each block does 16 rows; thread = (e, row-group).
// Input-row loads are wave-uniform (same addr across lanes) -> scalar cache.
// ---------------------------------------------------------------------------
__global__ __launch_bounds__(256) void proj_kernel(
    const float* __restrict__ query, const float* __restrict__ key,
    const float* __restrict__ value,
    const float* __restrict__ Wq, const float* __restrict__ bq,
    const float* __restrict__ Wk, const float* __restrict__ bk,
    const float* __restrict__ Wv, const float* __restrict__ bv,
    float* __restrict__ qws, float* __restrict__ kws, float* __restrict__ vws)
{
    const int t = threadIdx.x;
    const int e = t & 127;           // output embed index 0..127
    const int g = t >> 7;            // row group 0/1
    const int rbase = blockIdx.x * 16 + g * 8;

    float accq[8], acck[8], accv[8];
    const float bqv = bq[e], bkv = bk[e], bvv = bv[e];
#pragma unroll
    for (int r = 0; r < 8; ++r) { accq[r] = bqv; acck[r] = bkv; accv[r] = bvv; }

    const float4* Wq4 = (const float4*)(Wq + (size_t)e * 128);
    const float4* Wk4 = (const float4*)(Wk + (size_t)e * 128);
    for (int d4 = 0; d4 < 32; ++d4) {
        const float4 wq = Wq4[d4];
        const float4 wk = Wk4[d4];
#pragma unroll
        for (int r = 0; r < 8; ++r) {
            const float4 xq = *(const float4*)(query + (size_t)(rbase + r) * 128 + d4 * 4);
            const float4 xk = *(const float4*)(key   + (size_t)(rbase + r) * 128 + d4 * 4);
            accq[r] += wq.x*xq.x + wq.y*xq.y + wq.z*xq.z + wq.w*xq.w;
            acck[r] += wk.x*xk.x + wk.y*xk.y + wk.z*xk.z + wk.w*xk.w;
        }
    }
    const float4* Wv4 = (const float4*)(Wv + (size_t)e * 16);
#pragma unroll
    for (int d4 = 0; d4 < 4; ++d4) {
        const float4 wv = Wv4[d4];
#pragma unroll
        for (int r = 0; r < 8; ++r) {
            const float4 xv = *(const float4*)(value + (size_t)(rbase + r) * 16 + d4 * 4);
            accv[r] += wv.x*xv.x + wv.y*xv.y + wv.z*xv.z + wv.w*xv.w;
        }
    }

    const int h  = e >> 4;
    const int dd = e & 15;
#pragma unroll
    for (int r = 0; r < 8; ++r) {
        const int row = rbase + r;
        const int b = row >> 11;          // N = 2048
        const int n = row & 2047;
        const size_t idx = (((size_t)(b * HEADS + h) * NSEQ) + n) * HD + dd;
        qws[idx] = accq[r] * 0.25f;       // SCALING = 16^-0.5
        kws[idx] = acck[r];
        vws[idx] = accv[r];
    }
}

// ---------------------------------------------------------------------------
// Kernel 2: flash attention, fp32, online softmax.
// grid (32 q-tiles, 32 bh), block 256. Thread owns one q row (qi = t&63) and
// a contiguous quarter of the 2048 keys (ks = t>>6). K/V rows are read from
// global with wave-uniform addresses (lanes differ only in q). 4 partials
// per row combined through LDS at the end.
// ---------------------------------------------------------------------------
__global__ __launch_bounds__(256) void attn_kernel(
    const float* __restrict__ qws, const float* __restrict__ kws,
    const float* __restrict__ vws, float* __restrict__ ctxws)
{
    const int bh    = blockIdx.y;
    const int qbase = blockIdx.x * 64;
    const int t  = threadIdx.x;
    const int qi = t & 63;
    const int ks = t >> 6;

    __shared__ float red[4 * 64 * 18];   // (m, l, o[16]) per (ks, qi)

    const float4* qp = (const float4*)(qws + ((size_t)bh * NSEQ + qbase + qi) * HD);
    const float4 q0 = qp[0], q1 = qp[1], q2 = qp[2], q3 = qp[3];

    const float4* kb = (const float4*)(kws + (size_t)bh * NSEQ * HD);
    const float4* vb = (const float4*)(vws + (size_t)bh * NSEQ * HD);

    float m_i = -INFINITY, l_i = 0.0f;
    float4 o0 = {0,0,0,0}, o1 = {0,0,0,0}, o2 = {0,0,0,0}, o3 = {0,0,0,0};

    const int mbeg = ks * 512;
    const int mend = mbeg + 512;
    for (int m = mbeg; m < mend; ++m) {
        const float4 k0 = kb[m*4+0], k1 = kb[m*4+1], k2 = kb[m*4+2], k3 = kb[m*4+3];
        float s0 = q0.x*k0.x + q0.y*k0.y + q0.z*k0.z + q0.w*k0.w;
        float s1 = q1.x*k1.x + q1.y*k1.y + q1.z*k1.z + q1.w*k1.w;
        float s2 = q2.x*k2.x + q2.y*k2.y + q2.z*k2.z + q2.w*k2.w;
        float s3 = q3.x*k3.x + q3.y*k3.y + q3.z*k3.z + q3.w*k3.w;
        const float s = (s0 + s1) + (s2 + s3);
        const float4 v0 = vb[m*4+0], v1 = vb[m*4+1], v2 = vb[m*4+2], v3 = vb[m*4+3];
        if (s <= m_i) {
            // common path: max unchanged
            const float p = __expf(s - m_i);
            l_i += p;
            o0.x += p*v0.x; o0.y += p*v0.y; o0.z += p*v0.z; o0.w += p*v0.w;
            o1.x += p*v1.x; o1.y += p*v1.y; o1.z += p*v1.z; o1.w += p*v1.w;
            o2.x += p*v2.x; o2.y += p*v2.y; o2.z += p*v2.z; o2.w += p*v2.w;
            o3.x += p*v3.x; o3.y += p*v3.y; o3.z += p*v3.z; o3.w += p*v3.w;
        } else {
            // rare path: new max; p == 1 exactly. First iter: c = exp(-inf) = 0.
            const float c = __expf(m_i - s);
            m_i = s;
            l_i = l_i * c + 1.0f;
            o0.x = o0.x*c + v0.x; o0.y = o0.y*c + v0.y; o0.z = o0.z*c + v0.z; o0.w = o0.w*c + v0.w;
            o1.x = o1.x*c + v1.x; o1.y = o1.y*c + v1.y; o1.z = o1.z*c + v1.z; o1.w = o1.w*c + v1.w;
            o2.x = o2.x*c + v2.x; o2.y = o2.y*c + v2.y; o2.z = o2.z*c + v2.z; o2.w = o2.w*c + v2.w;
            o3.x = o3.x*c + v3.x; o3.y = o3.y*c + v3.y; o3.z = o3.z*c + v3.z; o3.w = o3.w*c + v3.w;
        }
    }

    // publish partials
    float* myred = &red[(ks * 64 + qi) * 18];
    myred[0] = m_i; myred[1] = l_i;
    myred[2]  = o0.x; myred[3]  = o0.y; myred[4]  = o0.z; myred[5]  = o0.w;
    myred[6]  = o1.x; myred[7]  = o1.y; myred[8]  = o1.z; myred[9]  = o1.w;
    myred[10] = o2.x; myred[11] = o2.y; myred[12] = o2.z; myred[13] = o2.w;
    myred[14] = o3.x; myred[15] = o3.y; myred[16] = o3.z; myred[17] = o3.w;
    __syncthreads();

    if (t < 64) {
        float mg = -INFINITY;
#pragma unroll
        for (int j = 0; j < 4; ++j) mg = fmaxf(mg, red[(j*64 + qi)*18 + 0]);
        float lg = 0.0f;
        float og[16];
#pragma unroll
        for (int d = 0; d < 16; ++d) og[d] = 0.0f;
#pragma unroll
        for (int j = 0; j < 4; ++j) {
            const float* rr = &red[(j*64 + qi)*18];
            const float w = __expf(rr[0] - mg);
            lg += rr[1] * w;
#pragma unroll
            for (int d = 0; d < 16; ++d) og[d] += rr[2 + d] * w;
        }
        const float inv = 1.0f / lg;
        float4* cp = (float4*)(ctxws + ((size_t)bh * NSEQ + qbase + qi) * HD);
        float4 c;
        c.x = og[0]*inv;  c.y = og[1]*inv;  c.z = og[2]*inv;  c.w = og[3]*inv;  cp[0] = c;
        c.x = og[4]*inv;  c.y = og[5]*inv;  c.z = og[6]*inv;  c.w = og[7]*inv;  cp[1] = c;
        c.x = og[8]*inv;  c.y = og[9]*inv;  c.z = og[10]*inv; c.w = og[11]*inv; cp[2] = c;
        c.x = og[12]*inv; c.y = og[13]*inv; c.z = og[14]*inv; c.w = og[15]*inv; cp[3] = c;
    }
}

// ---------------------------------------------------------------------------
// Kernel 3: output projection. out[row, j] = bo[j] + sum_e ctx[row, e]*Wo[j, e]
// ctx is head-major: ctx[row, h*16+d] = ctxws[((b*8+h)*N + n)*16 + d].
// grid 512, block 256; 16 rows/block, thread = (row_local, j).
// ---------------------------------------------------------------------------
__global__ __launch_bounds__(256) void outproj_kernel(
    const float* __restrict__ ctxws, const float* __restrict__ Wo,
    const float* __restrict__ bo, float* __restrict__ out)
{
    __shared__ float wo_s[16 * 132];     // padded stride 132 to dodge bank conflicts
    const int t = threadIdx.x;
    for (int i = t; i < 2048; i += 256) {
        const int j = i >> 7, e2 = i & 127;
        wo_s[j * 132 + e2] = Wo[i];
    }
    __syncthreads();

    const int rl = t >> 4, j = t & 15;
    const int row = blockIdx.x * 16 + rl;
    const int b = row >> 11, n = row & 2047;
    float acc = bo[j];
#pragma unroll
    for (int h = 0; h < 8; ++h) {
        const float4* cp4 = (const float4*)(ctxws + (((size_t)(b*8 + h) * NSEQ) + n) * HD);
#pragma unroll
        for (int d4 = 0; d4 < 4; ++d4) {
            const float4 cc = cp4[d4];
            const float* wp = &wo_s[j * 132 + h * 16 + d4 * 4];
            acc += cc.x*wp[0] + cc.y*wp[1] + cc.z*wp[2] + cc.w*wp[3];
        }
    }
    out[(size_t)row * 16 + j] = acc;
}

// ---------------------------------------------------------------------------
extern "C" void kernel_launch(void* const* d_in, const int* in_sizes, int n_in,
                              void* d_out, int out_size, void* d_ws, size_t ws_size,
                              hipStream_t stream)
{
    const float* query = (const float*)d_in[0];
    const float* key_  = (const float*)d_in[1];
    const float* value = (const float*)d_in[2];
    const float* Wq = (const float*)d_in[3];
    const float* bq = (const float*)d_in[4];
    const float* Wk = (const float*)d_in[5];
    const float* bk = (const float*)d_in[6];
    const float* Wv = (const float*)d_in[7];
    const float* bv = (const float*)d_in[8];
    const float* Wo = (const float*)d_in[9];
    const float* bo = (const float*)d_in[10];
    float* out = (float*)d_out;

    // Workspace: 4 arrays of [32][2048][16] fp32 = 4 MB each, 16 MB total.
    float* qws = (float*)d_ws;
    float* kws = qws + (1u << 20);
    float* vws = qws + (2u << 20);
    float* ctx = qws + (3u << 20);

    proj_kernel<<<dim3(512), dim3(256), 0, stream>>>(
        query, key_, value, Wq, bq, Wk, bk, Wv, bv, qws, kws, vws);
    attn_kernel<<<dim3(32, 32), dim3(256), 0, stream>>>(qws, kws, vws, ctx);
    outproj_kernel<<<dim3(512), dim3(256), 0, stream>>>(ctx, Wo, bo, out);
}

// Round 2
// 225.510 us; speedup vs baseline: 2.7798x; 2.7798x over previous
//
#include <hip/hip_runtime.h>
#include <math.h>

typedef unsigned short ushort_t;
typedef unsigned int uint_t;
typedef __bf16 bf16x8 __attribute__((ext_vector_type(8)));
typedef float f32x4 __attribute__((ext_vector_type(4)));

#define NSEQ 2048
#define BH   32        // B*H
// q pre-scale: HEAD_DIM^-0.5 * log2(e) so softmax runs in exp2 domain
#define QSCALE 0.3606737602222409f

__device__ __forceinline__ float exp2_fast(float x) {
#if __has_builtin(__builtin_amdgcn_exp2f)
    return __builtin_amdgcn_exp2f(x);
#else
    return exp2f(x);
#endif
}

// float -> bf16 bits, round-to-nearest-even
__device__ __forceinline__ ushort_t f2bf(float x) {
    uint_t u = __float_as_uint(x);
    u += 0x7FFFu + ((u >> 16) & 1u);
    return (ushort_t)(u >> 16);
}
__device__ __forceinline__ float bf2f(ushort_t h) {
    return __uint_as_float(((uint_t)h) << 16);
}
// pack two floats as bf16 pair (round half-up; inputs are >=0 softmax weights)
__device__ __forceinline__ uint_t pkbf(float a, float b) {
    return ((__float_as_uint(a) + 0x8000u) >> 16) |
           ((__float_as_uint(b) + 0x8000u) & 0xFFFF0000u);
}

// ---------------------------------------------------------------------------
// Kernel 1: fused Q/K/V projection -> bf16 hi/lo workspace arrays.
//   q_hi/q_lo, k_hi/k_lo : [BH][N][16] bf16 (q pre-scaled by QSCALE)
//   vt                   : [BH][16][N] bf16 (V transposed)
// grid 2048, block 256: 4 rows/block, 2 rows/thread -> 8 blocks/CU, full occ.
// ---------------------------------------------------------------------------
__global__ __launch_bounds__(256) void proj_kernel(
    const float* __restrict__ query, const float* __restrict__ key,
    const float* __restrict__ value,
    const float* __restrict__ Wq, const float* __restrict__ bq,
    const float* __restrict__ Wk, const float* __restrict__ bk,
    const float* __restrict__ Wv, const float* __restrict__ bv,
    ushort_t* __restrict__ q_hi, ushort_t* __restrict__ q_lo,
    ushort_t* __restrict__ k_hi, ushort_t* __restrict__ k_lo,
    ushort_t* __restrict__ vt)
{
    const int t  = threadIdx.x;
    const int e  = t & 127;          // output embed col
    const int rh = t >> 7;           // 0/1
    const int rbase = blockIdx.x * 4 + rh * 2;   // 2 consecutive rows

    float accq[2], acck[2], accv[2];
    const float bqv = bq[e], bkv = bk[e], bvv = bv[e];
    accq[0] = accq[1] = bqv; acck[0] = acck[1] = bkv; accv[0] = accv[1] = bvv;

    const float4* Wq4 = (const float4*)(Wq + (size_t)e * 128);
    const float4* Wk4 = (const float4*)(Wk + (size_t)e * 128);
#pragma unroll 8
    for (int d4 = 0; d4 < 32; ++d4) {
        const float4 wq = Wq4[d4];
        const float4 wk = Wk4[d4];
#pragma unroll
        for (int r = 0; r < 2; ++r) {
            const float4 xq = *(const float4*)(query + (size_t)(rbase + r) * 128 + d4 * 4);
            const float4 xk = *(const float4*)(key   + (size_t)(rbase + r) * 128 + d4 * 4);
            accq[r] += wq.x*xq.x + wq.y*xq.y + wq.z*xq.z + wq.w*xq.w;
            acck[r] += wk.x*xk.x + wk.y*xk.y + wk.z*xk.z + wk.w*xk.w;
        }
    }
    const float4* Wv4 = (const float4*)(Wv + (size_t)e * 16);
#pragma unroll
    for (int d4 = 0; d4 < 4; ++d4) {
        const float4 wv = Wv4[d4];
#pragma unroll
        for (int r = 0; r < 2; ++r) {
            const float4 xv = *(const float4*)(value + (size_t)(rbase + r) * 16 + d4 * 4);
            accv[r] += wv.x*xv.x + wv.y*xv.y + wv.z*xv.z + wv.w*xv.w;
        }
    }

    const int h = e >> 4, dd = e & 15;
    const int b = rbase >> 11;                 // both rows in same b (4-aligned block)
    const int bh = b * 8 + h;
    ushort_t vh[2];
#pragma unroll
    for (int r = 0; r < 2; ++r) {
        const int n = (rbase + r) & 2047;
        const size_t idx = ((size_t)bh * NSEQ + n) * 16 + dd;
        float qs = accq[r] * QSCALE;
        ushort_t qh = f2bf(qs);
        q_hi[idx] = qh;
        q_lo[idx] = f2bf(qs - bf2f(qh));
        float kv = acck[r];
        ushort_t kh = f2bf(kv);
        k_hi[idx] = kh;
        k_lo[idx] = f2bf(kv - bf2f(kh));
        vh[r] = f2bf(accv[r]);
    }
    const int n0 = rbase & 2047;
    *(uint_t*)(vt + ((size_t)bh * 16 + dd) * NSEQ + n0) =
        (uint_t)vh[0] | ((uint_t)vh[1] << 16);
}

// ---------------------------------------------------------------------------
// Kernel 2: flash attention on MFMA (split-bf16 QK^T, bf16 PV).
// Per wave: 16 q rows, loop over 64 blocks of 32 keys.
//   S^T[key][q]: A=[khi|klo] x B=[qhi|qhi]  +  A x B=[qlo|0]  (2 MFMAs/16keys)
//   O^T[vd][q] += V^T x P^T (1 MFMA),  l[q] += ones x P^T (1 MFMA)
// P transposes through per-wave LDS (stride 40 ushorts: aligned + bank-clean).
// grid (32 qtiles, 32 bh), block 256 (4 independent waves).
// ---------------------------------------------------------------------------
__global__ __launch_bounds__(256) void attn_kernel(
    const ushort_t* __restrict__ q_hi, const ushort_t* __restrict__ q_lo,
    const ushort_t* __restrict__ k_hi, const ushort_t* __restrict__ k_lo,
    const ushort_t* __restrict__ vt, float* __restrict__ ctx)
{
    const int t    = threadIdx.x;
    const int wave = t >> 6;
    const int l    = t & 63;
    const int col  = l & 15;          // q-col / key-row / vd, per fragment
    const int g    = l >> 4;          // lane group 0..3

    const int bh = blockIdx.y;
    const int qb = blockIdx.x * 64 + wave * 16;

    __shared__ __align__(16) ushort_t lds_p[4][16 * 40];
    ushort_t* pbuf = lds_p[wave];

    union BF8 { ushort_t u[8]; bf16x8 v; };
    BF8 Uz; BF8 Uo;
#pragma unroll
    for (int i = 0; i < 8; ++i) { Uz.u[i] = 0; Uo.u[i] = 0x3F80; }
    const bf16x8 zf = Uz.v, ones = Uo.v;

    // Q B-fragments (built once): B1=[qhi|qhi], B2=[qlo|0]
    const size_t qoff = ((size_t)(bh * NSEQ + qb + col)) * 16 + (g & 1) * 8;
    const bf16x8 bq1 = *(const bf16x8*)(q_hi + qoff);
    bf16x8 bq2 = *(const bf16x8*)(q_lo + qoff);
    bq2 = (g < 2) ? bq2 : zf;

    // K A-fragment base: groups 0,1 read k_hi; groups 2,3 read k_lo
    const ushort_t* ksel = (g < 2) ? k_hi : k_lo;
    const ushort_t* aptr = ksel + ((size_t)(bh * NSEQ + col)) * 16 + (g & 1) * 8;
    // V^T A-fragment base: row vd = col, keys 8g..8g+7
    const ushort_t* vptr = vt + ((size_t)(bh * 16 + col)) * NSEQ + g * 8;

    f32x4 o    = {0.f, 0.f, 0.f, 0.f};
    f32x4 lacc = {0.f, 0.f, 0.f, 0.f};
    float m_run = -INFINITY;

    // prefetch kb=0
    bf16x8 a1 = *(const bf16x8*)(aptr);          // keys 0..15 of block
    bf16x8 a2 = *(const bf16x8*)(aptr + 256);    // keys 16..31
    bf16x8 av = *(const bf16x8*)(vptr);

    for (int kb = 0; kb < 64; ++kb) {
        const int kn = (kb + 1) & 63;            // wrap: harmless dummy on last
        bf16x8 na1 = *(const bf16x8*)(aptr + (size_t)kn * 512);
        bf16x8 na2 = *(const bf16x8*)(aptr + (size_t)kn * 512 + 256);
        bf16x8 nav = *(const bf16x8*)(vptr + (size_t)kn * 32);

        // scores S^T (two 16-key sub-tiles)
        f32x4 z = {0.f, 0.f, 0.f, 0.f};
        f32x4 st1 = __builtin_amdgcn_mfma_f32_16x16x32_bf16(a1, bq2, z, 0, 0, 0);
        st1       = __builtin_amdgcn_mfma_f32_16x16x32_bf16(a1, bq1, st1, 0, 0, 0);
        f32x4 st2 = __builtin_amdgcn_mfma_f32_16x16x32_bf16(a2, bq2, z, 0, 0, 0);
        st2       = __builtin_amdgcn_mfma_f32_16x16x32_bf16(a2, bq1, st2, 0, 0, 0);

        // block max over 32 keys for this q column
        float tm = fmaxf(fmaxf(fmaxf(st1[0], st1[1]), fmaxf(st1[2], st1[3])),
                         fmaxf(fmaxf(st2[0], st2[1]), fmaxf(st2[2], st2[3])));
        tm = fmaxf(tm, __shfl_xor(tm, 16));
        tm = fmaxf(tm, __shfl_xor(tm, 32));

        const float m_new = fmaxf(m_run, tm);
        const float alpha = exp2_fast(m_run - m_new);
        m_run = m_new;

        float p0 = exp2_fast(st1[0] - m_new);
        float p1 = exp2_fast(st1[1] - m_new);
        float p2 = exp2_fast(st1[2] - m_new);
        float p3 = exp2_fast(st1[3] - m_new);
        float p4 = exp2_fast(st2[0] - m_new);
        float p5 = exp2_fast(st2[1] - m_new);
        float p6 = exp2_fast(st2[2] - m_new);
        float p7 = exp2_fast(st2[3] - m_new);

        o[0] *= alpha; o[1] *= alpha; o[2] *= alpha; o[3] *= alpha;
        lacc[0] *= alpha; lacc[1] *= alpha; lacc[2] *= alpha; lacc[3] *= alpha;

        // P^T -> LDS [q][key], bf16
        uint2 w1; w1.x = pkbf(p0, p1); w1.y = pkbf(p2, p3);
        uint2 w2; w2.x = pkbf(p4, p5); w2.y = pkbf(p6, p7);
        *(uint2*)(pbuf + col * 40 + 4 * g)      = w1;   // keys 4g..4g+3
        *(uint2*)(pbuf + col * 40 + 16 + 4 * g) = w2;   // keys 16+4g..
        // B-frag read: keys 8g..8g+7 for col q (same-wave write->read)
        const bf16x8 bp = *(const bf16x8*)(pbuf + col * 40 + 8 * g);

        o    = __builtin_amdgcn_mfma_f32_16x16x32_bf16(av,   bp, o,    0, 0, 0);
        lacc = __builtin_amdgcn_mfma_f32_16x16x32_bf16(ones, bp, lacc, 0, 0, 0);

        a1 = na1; a2 = na2; av = nav;
    }

    const float linv = 1.0f / lacc[0];
    f32x4 res;
    res[0] = o[0] * linv; res[1] = o[1] * linv;
    res[2] = o[2] * linv; res[3] = o[3] * linv;
    // O^T C-layout: col=q, rows vd=4g..4g+3 -> one float4 per lane
    *(f32x4*)(ctx + ((size_t)(bh * NSEQ + qb + col)) * 16 + 4 * g) = res;
}

// ---------------------------------------------------------------------------
// Kernel 3: output projection (fp32). out[row,j] = bo[j] + sum_e ctx*Wo[j,e]
// ctx is head-major [BH][N][16].
// ---------------------------------------------------------------------------
__global__ __launch_bounds__(256) void outproj_kernel(
    const float* __restrict__ ctxws, const float* __restrict__ Wo,
    const float* __restrict__ bo, float* __restrict__ out)
{
    __shared__ float wo_s[16 * 132];
    const int t = threadIdx.x;
    for (int i = t; i < 2048; i += 256) {
        const int j = i >> 7, e2 = i & 127;
        wo_s[j * 132 + e2] = Wo[i];
    }
    __syncthreads();

    const int rl = t >> 4, j = t & 15;
    const int row = blockIdx.x * 16 + rl;
    const int b = row >> 11, n = row & 2047;
    float acc = bo[j];
#pragma unroll
    for (int h = 0; h < 8; ++h) {
        const float4* cp4 = (const float4*)(ctxws + (((size_t)(b*8 + h) * NSEQ) + n) * 16);
#pragma unroll
        for (int d4 = 0; d4 < 4; ++d4) {
            const float4 cc = cp4[d4];
            const float* wp = &wo_s[j * 132 + h * 16 + d4 * 4];
            acc += cc.x*wp[0] + cc.y*wp[1] + cc.z*wp[2] + cc.w*wp[3];
        }
    }
    out[(size_t)row * 16 + j] = acc;
}

// ---------------------------------------------------------------------------
extern "C" void kernel_launch(void* const* d_in, const int* in_sizes, int n_in,
                              void* d_out, int out_size, void* d_ws, size_t ws_size,
                              hipStream_t stream)
{
    const float* query = (const float*)d_in[0];
    const float* key_  = (const float*)d_in[1];
    const float* value = (const float*)d_in[2];
    const float* Wq = (const float*)d_in[3];
    const float* bq = (const float*)d_in[4];
    const float* Wk = (const float*)d_in[5];
    const float* bk = (const float*)d_in[6];
    const float* Wv = (const float*)d_in[7];
    const float* bv = (const float*)d_in[8];
    const float* Wo = (const float*)d_in[9];
    const float* bo = (const float*)d_in[10];
    float* out = (float*)d_out;

    // Workspace: 5 bf16 arrays of 1M elements (2 MB each) + ctx fp32 (4 MB)
    ushort_t* q_hi = (ushort_t*)d_ws;
    ushort_t* q_lo = q_hi + (1u << 20);
    ushort_t* k_hi = q_hi + (2u << 20);
    ushort_t* k_lo = q_hi + (3u << 20);
    ushort_t* vt   = q_hi + (4u << 20);
    float*    ctx  = (float*)((char*)d_ws + (10u << 20));

    proj_kernel<<<dim3(2048), dim3(256), 0, stream>>>(
        query, key_, value, Wq, bq, Wk, bk, Wv, bv,
        q_hi, q_lo, k_hi, k_lo, vt);
    attn_kernel<<<dim3(32, 32), dim3(256), 0, stream>>>(
        q_hi, q_lo, k_hi, k_lo, vt, ctx);
    outproj_kernel<<<dim3(512), dim3(256), 0, stream>>>(ctx, Wo, bo, out);
}

// Round 3
// 146.267 us; speedup vs baseline: 4.2858x; 1.5418x over previous
//
#include <hip/hip_runtime.h>
#include <math.h>

typedef unsigned short ushort_t;
typedef unsigned int uint_t;
typedef __bf16 bf16x8 __attribute__((ext_vector_type(8)));
typedef float f32x4 __attribute__((ext_vector_type(4)));

#define NSEQ 2048
#define BH   32        // B*H
// q pre-scale: HEAD_DIM^-0.5 * log2(e) so softmax runs in exp2 domain
#define QSCALE 0.3606737602222409f

__device__ __forceinline__ float exp2_fast(float x) {
#if __has_builtin(__builtin_amdgcn_exp2f)
    return __builtin_amdgcn_exp2f(x);
#else
    return exp2f(x);
#endif
}

// float -> bf16 bits, round-to-nearest-even
__device__ __forceinline__ ushort_t f2bf(float x) {
    uint_t u = __float_as_uint(x);
    u += 0x7FFFu + ((u >> 16) & 1u);
    return (ushort_t)(u >> 16);
}
__device__ __forceinline__ float bf2f(ushort_t h) {
    return __uint_as_float(((uint_t)h) << 16);
}
// pack two floats as bf16 pair (round half-up; inputs are >=0 softmax weights)
__device__ __forceinline__ uint_t pkbf(float a, float b) {
    return ((__float_as_uint(a) + 0x8000u) >> 16) |
           ((__float_as_uint(b) + 0x8000u) & 0xFFFF0000u);
}

union U8 { ushort_t u[8]; bf16x8 v; uint4 q; };
union F8 { float f[8]; float4 v4[2]; };

// ---------------------------------------------------------------------------
// Kernel 0: pack Wq/Wk into MFMA-B-fragment order, split bf16 hi/lo.
// Layout: wpk[mat][((ct*4 + f)*64 + lane)*8 + j]
//   = W_mat[ct*16 + (lane&15)][f*32 + (lane>>4)*8 + j]
// One thread per (mat, ct, f, lane): 4096 threads.
// ---------------------------------------------------------------------------
__global__ __launch_bounds__(256) void wpack_kernel(
    const float* __restrict__ Wq, const float* __restrict__ Wk,
    ushort_t* __restrict__ wpk_hi, ushort_t* __restrict__ wpk_lo)
{
    const int idx  = blockIdx.x * 256 + threadIdx.x;   // 0..4095
    const int lane = idx & 63;
    const int f    = (idx >> 6) & 3;
    const int ct   = (idx >> 8) & 7;
    const int mat  = idx >> 11;
    const float* W = mat ? Wk : Wq;
    const float* src = W + (size_t)(ct * 16 + (lane & 15)) * 128
                         + f * 32 + (lane >> 4) * 8;
    F8 x; x.v4[0] = *(const float4*)src; x.v4[1] = *(const float4*)(src + 4);
    U8 hi, lo;
#pragma unroll
    for (int j = 0; j < 8; ++j) {
        const ushort_t h = f2bf(x.f[j]);
        hi.u[j] = h;
        lo.u[j] = f2bf(x.f[j] - bf2f(h));
    }
    const size_t dst = (size_t)mat * 16384 + ((size_t)(ct * 4 + f) * 64 + lane) * 8;
    *(uint4*)(wpk_hi + dst) = hi.q;
    *(uint4*)(wpk_lo + dst) = lo.q;
}

// ---------------------------------------------------------------------------
// Kernel 1: Q/K projections on MFMA (split-bf16, 3 products: XhWh+XlWh+XhWl),
// V projection + V^T store on VALU. 512 blocks x 256 threads; 16 rows/block.
// Waves 0,1 -> Q (heads 0-3 / 4-7); waves 2,3 -> K.
// Outputs: q_hi/q_lo/k_hi/k_lo [BH][N][16] bf16 (q pre-scaled by QSCALE),
//          vt [BH][16][N] bf16.
// ---------------------------------------------------------------------------
__global__ __launch_bounds__(256, 2) void proj_kernel(
    const float* __restrict__ query, const float* __restrict__ key,
    const float* __restrict__ value,
    const float* __restrict__ bq, const float* __restrict__ bk,
    const float* __restrict__ Wv, const float* __restrict__ bv,
    const ushort_t* __restrict__ wpk_hi, const ushort_t* __restrict__ wpk_lo,
    ushort_t* __restrict__ q_hi, ushort_t* __restrict__ q_lo,
    ushort_t* __restrict__ k_hi, ushort_t* __restrict__ k_lo,
    ushort_t* __restrict__ vt)
{
    const int t   = threadIdx.x;
    const int w   = t >> 6;
    const int l   = t & 63;
    const int n16 = l & 15;          // A row (m) / B col (n) / C col
    const int g   = l >> 4;          // lane quad
    const int rbase = blockIdx.x * 16;
    const int b = rbase >> 11;       // batch (16 | 2048, so uniform per block)

    const int isK    = w >> 1;       // 0: Q-proj, 1: K-proj
    const int cthalf = (w & 1) * 4;  // head-tile base for this wave

    // ---- A fragments: X rows rbase+n16, k = f*32 + g*8 + j, fp32->hi/lo ----
    const float* X = isK ? key : query;
    const float* xrow = X + (size_t)(rbase + n16) * 128 + g * 8;
    bf16x8 ah[4], al[4];
#pragma unroll
    for (int f = 0; f < 4; ++f) {
        F8 x;
        x.v4[0] = *(const float4*)(xrow + f * 32);
        x.v4[1] = *(const float4*)(xrow + f * 32 + 4);
        U8 hi, lo;
#pragma unroll
        for (int j = 0; j < 8; ++j) {
            const ushort_t h = f2bf(x.f[j]);
            hi.u[j] = h;
            lo.u[j] = f2bf(x.f[j] - bf2f(h));
        }
        ah[f] = hi.v; al[f] = lo.v;
    }

    // ---- B fragments: packed, coalesced 16B/lane ----
    bf16x8 bhfr[4][4], blfr[4][4];
#pragma unroll
    for (int ctl = 0; ctl < 4; ++ctl) {
#pragma unroll
        for (int f = 0; f < 4; ++f) {
            const size_t o = (size_t)isK * 16384
                           + ((size_t)((cthalf + ctl) * 4 + f) * 64 + l) * 8;
            bhfr[ctl][f] = *(const bf16x8*)(wpk_hi + o);
            blfr[ctl][f] = *(const bf16x8*)(wpk_lo + o);
        }
    }

    // ---- GEMM + epilogue ----
    const float* bias = isK ? bk : bq;
    ushort_t* dhi = isK ? k_hi : q_hi;
    ushort_t* dlo = isK ? k_lo : q_lo;
    const float scale = isK ? 1.0f : QSCALE;
    const int nbase = (rbase & 2047) + g * 4;

#pragma unroll
    for (int ctl = 0; ctl < 4; ++ctl) {
        const int h = cthalf + ctl;
        const float bval = bias[h * 16 + n16];
        f32x4 acc = {bval, bval, bval, bval};
#pragma unroll
        for (int f = 0; f < 4; ++f) {
            acc = __builtin_amdgcn_mfma_f32_16x16x32_bf16(ah[f], bhfr[ctl][f], acc, 0, 0, 0);
            acc = __builtin_amdgcn_mfma_f32_16x16x32_bf16(al[f], bhfr[ctl][f], acc, 0, 0, 0);
            acc = __builtin_amdgcn_mfma_f32_16x16x32_bf16(ah[f], blfr[ctl][f], acc, 0, 0, 0);
        }
        const size_t abase = ((size_t)(b * 8 + h) * NSEQ + nbase) * 16 + n16;
#pragma unroll
        for (int r = 0; r < 3 + 1; ++r) {
            const float vq = acc[r] * scale;
            const ushort_t hh = f2bf(vq);
            dhi[abase + (size_t)r * 16] = hh;
            dlo[abase + (size_t)r * 16] = f2bf(vq - bf2f(hh));
        }
    }

    // ---- V projection (VALU, K=16) + vt transpose store ----
    const int e  = t & 127;
    const int rh = t >> 7;
    const int r0 = rbase + rh * 8;
    const float4* Wv4 = (const float4*)(Wv + (size_t)e * 16);
    const float4 wv0 = Wv4[0], wv1 = Wv4[1], wv2 = Wv4[2], wv3 = Wv4[3];
    const float bvv = bv[e];
    U8 vpk;
#pragma unroll
    for (int r = 0; r < 8; ++r) {
        const float4* xv4 = (const float4*)(value + (size_t)(r0 + r) * 16);
        const float4 x0 = xv4[0], x1 = xv4[1], x2 = xv4[2], x3 = xv4[3];
        float a = bvv;
        a += wv0.x*x0.x + wv0.y*x0.y + wv0.z*x0.z + wv0.w*x0.w;
        a += wv1.x*x1.x + wv1.y*x1.y + wv1.z*x1.z + wv1.w*x1.w;
        a += wv2.x*x2.x + wv2.y*x2.y + wv2.z*x2.z + wv2.w*x2.w;
        a += wv3.x*x3.x + wv3.y*x3.y + wv3.z*x3.z + wv3.w*x3.w;
        vpk.u[r] = f2bf(a);
    }
    const int hv = e >> 4, dd = e & 15;
    *(uint4*)(vt + ((size_t)(b * 8 + hv) * 16 + dd) * NSEQ + (r0 & 2047)) = vpk.q;
}

// ---------------------------------------------------------------------------
// Kernel 2: flash attention on MFMA (split-bf16 QK^T, bf16 PV). Unchanged.
// ---------------------------------------------------------------------------
__global__ __launch_bounds__(256) void attn_kernel(
    const ushort_t* __restrict__ q_hi, const ushort_t* __restrict__ q_lo,
    const ushort_t* __restrict__ k_hi, const ushort_t* __restrict__ k_lo,
    const ushort_t* __restrict__ vt, float* __restrict__ ctx)
{
    const int t    = threadIdx.x;
    const int wave = t >> 6;
    const int l    = t & 63;
    const int col  = l & 15;
    const int g    = l >> 4;

    const int bh = blockIdx.y;
    const int qb = blockIdx.x * 64 + wave * 16;

    __shared__ __align__(16) ushort_t lds_p[4][16 * 40];
    ushort_t* pbuf = lds_p[wave];

    U8 Uz, Uo;
#pragma unroll
    for (int i = 0; i < 8; ++i) { Uz.u[i] = 0; Uo.u[i] = 0x3F80; }
    const bf16x8 zf = Uz.v, ones = Uo.v;

    const size_t qoff = ((size_t)(bh * NSEQ + qb + col)) * 16 + (g & 1) * 8;
    const bf16x8 bq1 = *(const bf16x8*)(q_hi + qoff);
    bf16x8 bq2 = *(const bf16x8*)(q_lo + qoff);
    bq2 = (g < 2) ? bq2 : zf;

    const ushort_t* ksel = (g < 2) ? k_hi : k_lo;
    const ushort_t* aptr = ksel + ((size_t)(bh * NSEQ + col)) * 16 + (g & 1) * 8;
    const ushort_t* vptr = vt + ((size_t)(bh * 16 + col)) * NSEQ + g * 8;

    f32x4 o    = {0.f, 0.f, 0.f, 0.f};
    f32x4 lacc = {0.f, 0.f, 0.f, 0.f};
    float m_run = -INFINITY;

    bf16x8 a1 = *(const bf16x8*)(aptr);
    bf16x8 a2 = *(const bf16x8*)(aptr + 256);
    bf16x8 av = *(const bf16x8*)(vptr);

    for (int kb = 0; kb < 64; ++kb) {
        const int kn = (kb + 1) & 63;
        bf16x8 na1 = *(const bf16x8*)(aptr + (size_t)kn * 512);
        bf16x8 na2 = *(const bf16x8*)(aptr + (size_t)kn * 512 + 256);
        bf16x8 nav = *(const bf16x8*)(vptr + (size_t)kn * 32);

        f32x4 z = {0.f, 0.f, 0.f, 0.f};
        f32x4 st1 = __builtin_amdgcn_mfma_f32_16x16x32_bf16(a1, bq2, z, 0, 0, 0);
        st1       = __builtin_amdgcn_mfma_f32_16x16x32_bf16(a1, bq1, st1, 0, 0, 0);
        f32x4 st2 = __builtin_amdgcn_mfma_f32_16x16x32_bf16(a2, bq2, z, 0, 0, 0);
        st2       = __builtin_amdgcn_mfma_f32_16x16x32_bf16(a2, bq1, st2, 0, 0, 0);

        float tm = fmaxf(fmaxf(fmaxf(st1[0], st1[1]), fmaxf(st1[2], st1[3])),
                         fmaxf(fmaxf(st2[0], st2[1]), fmaxf(st2[2], st2[3])));
        tm = fmaxf(tm, __shfl_xor(tm, 16));
        tm = fmaxf(tm, __shfl_xor(tm, 32));

        const float m_new = fmaxf(m_run, tm);
        const float alpha = exp2_fast(m_run - m_new);
        m_run = m_new;

        float p0 = exp2_fast(st1[0] - m_new);
        float p1 = exp2_fast(st1[1] - m_new);
        float p2 = exp2_fast(st1[2] - m_new);
        float p3 = exp2_fast(st1[3] - m_new);
        float p4 = exp2_fast(st2[0] - m_new);
        float p5 = exp2_fast(st2[1] - m_new);
        float p6 = exp2_fast(st2[2] - m_new);
        float p7 = exp2_fast(st2[3] - m_new);

        o[0] *= alpha; o[1] *= alpha; o[2] *= alpha; o[3] *= alpha;
        lacc[0] *= alpha; lacc[1] *= alpha; lacc[2] *= alpha; lacc[3] *= alpha;

        uint2 w1; w1.x = pkbf(p0, p1); w1.y = pkbf(p2, p3);
        uint2 w2; w2.x = pkbf(p4, p5); w2.y = pkbf(p6, p7);
        *(uint2*)(pbuf + col * 40 + 4 * g)      = w1;
        *(uint2*)(pbuf + col * 40 + 16 + 4 * g) = w2;
        const bf16x8 bp = *(const bf16x8*)(pbuf + col * 40 + 8 * g);

        o    = __builtin_amdgcn_mfma_f32_16x16x32_bf16(av,   bp, o,    0, 0, 0);
        lacc = __builtin_amdgcn_mfma_f32_16x16x32_bf16(ones, bp, lacc, 0, 0, 0);

        a1 = na1; a2 = na2; av = nav;
    }

    const float linv = 1.0f / lacc[0];
    f32x4 res;
    res[0] = o[0] * linv; res[1] = o[1] * linv;
    res[2] = o[2] * linv; res[3] = o[3] * linv;
    *(f32x4*)(ctx + ((size_t)(bh * NSEQ + qb + col)) * 16 + 4 * g) = res;
}

// ---------------------------------------------------------------------------
// Kernel 3: output projection (fp32). Unchanged.
// ---------------------------------------------------------------------------
__global__ __launch_bounds__(256) void outproj_kernel(
    const float* __restrict__ ctxws, const float* __restrict__ Wo,
    const float* __restrict__ bo, float* __restrict__ out)
{
    __shared__ float wo_s[16 * 132];
    const int t = threadIdx.x;
    for (int i = t; i < 2048; i += 256) {
        const int j = i >> 7, e2 = i & 127;
        wo_s[j * 132 + e2] = Wo[i];
    }
    __syncthreads();

    const int rl = t >> 4, j = t & 15;
    const int row = blockIdx.x * 16 + rl;
    const int b = row >> 11, n = row & 2047;
    float acc = bo[j];
#pragma unroll
    for (int h = 0; h < 8; ++h) {
        const float4* cp4 = (const float4*)(ctxws + (((size_t)(b*8 + h) * NSEQ) + n) * 16);
#pragma unroll
        for (int d4 = 0; d4 < 4; ++d4) {
            const float4 cc = cp4[d4];
            const float* wp = &wo_s[j * 132 + h * 16 + d4 * 4];
            acc += cc.x*wp[0] + cc.y*wp[1] + cc.z*wp[2] + cc.w*wp[3];
        }
    }
    out[(size_t)row * 16 + j] = acc;
}

// ---------------------------------------------------------------------------
extern "C" void kernel_launch(void* const* d_in, const int* in_sizes, int n_in,
                              void* d_out, int out_size, void* d_ws, size_t ws_size,
                              hipStream_t stream)
{
    const float* query = (const float*)d_in[0];
    const float* key_  = (const float*)d_in[1];
    const float* value = (const float*)d_in[2];
    const float* Wq = (const float*)d_in[3];
    const float* bq = (const float*)d_in[4];
    const float* Wk = (const float*)d_in[5];
    const float* bk = (const float*)d_in[6];
    const float* Wv = (const float*)d_in[7];
    const float* bv = (const float*)d_in[8];
    const float* Wo = (const float*)d_in[9];
    const float* bo = (const float*)d_in[10];
    float* out = (float*)d_out;

    // Workspace: 5 bf16 arrays (2 MB each) + ctx fp32 (4 MB) + packed W (128 KB)
    ushort_t* q_hi = (ushort_t*)d_ws;
    ushort_t* q_lo = q_hi + (1u << 20);
    ushort_t* k_hi = q_hi + (2u << 20);
    ushort_t* k_lo = q_hi + (3u << 20);
    ushort_t* vt   = q_hi + (4u << 20);
    float*    ctx  = (float*)((char*)d_ws + (10u << 20));
    ushort_t* wpk_hi = (ushort_t*)((char*)d_ws + (14u << 20));
    ushort_t* wpk_lo = wpk_hi + 32768;

    wpack_kernel<<<dim3(16), dim3(256), 0, stream>>>(Wq, Wk, wpk_hi, wpk_lo);
    proj_kernel<<<dim3(512), dim3(256), 0, stream>>>(
        query, key_, value, bq, bk, Wv, bv, wpk_hi, wpk_lo,
        q_hi, q_lo, k_hi, k_lo, vt);
    attn_kernel<<<dim3(32, 32), dim3(256), 0, stream>>>(
        q_hi, q_lo, k_hi, k_lo, vt, ctx);
    outproj_kernel<<<dim3(512), dim3(256), 0, stream>>>(ctx, Wo, bo, out);
}